// Round 2
// 9193.179 us; speedup vs baseline: 1.3573x; 1.3573x over previous
//
#include <hip/hip_runtime.h>
#include <math.h>

#define L_ 4
#define B_ 4
#define S_ 1024
#define D_ 768
#define F_ 3072
#define E_ 4
#define V_ 256
#define H_ 12
#define DH_ 64
#define T_ (B_*S_)
#define QKV_LD (3*D_)

typedef __attribute__((ext_vector_type(8))) __bf16 bf16x8;
typedef __attribute__((ext_vector_type(4))) float f32x4;
typedef __attribute__((ext_vector_type(8))) unsigned short u16x8;

__device__ __forceinline__ ushort f2bf(float x) {
    union { float f; unsigned int u; } c; c.f = x;
    unsigned int u = c.u;
    unsigned int r = (u + 0x7fffu + ((u >> 16) & 1u)) >> 16;   // RTN-even
    return (ushort)r;
}
__device__ __forceinline__ float bf2f(ushort u) {
    union { unsigned int u; float f; } c; c.u = ((unsigned int)u) << 16;
    return c.f;
}
// exact 3-way split: v == bf2f(h)+bf2f(l)+bf2f(q) bit-exactly (8+8+8 >= 24 mantissa bits)
__device__ __forceinline__ void split3(float v, ushort& h, ushort& l, ushort& q) {
    h = f2bf(v);
    float r1 = v - bf2f(h);
    l = f2bf(r1);
    float r2 = r1 - bf2f(l);
    q = f2bf(r2);
}

__device__ __forceinline__ float gelu_f(float x) {
    return 0.5f * x * (1.f + tanhf(0.7978845608028654f * (x + 0.044715f * x * x * x)));
}

// ---------------- embedding lookup into padded bf16 3-plane buffers [B][S+2][D] ----------------
__global__ __launch_bounds__(256) void embed_pad_k(const int* __restrict__ text,
                                                   const float* __restrict__ embed,
                                                   ushort* __restrict__ xpH,
                                                   ushort* __restrict__ xpL,
                                                   ushort* __restrict__ xpQ) {
    int idx = blockIdx.x * 256 + threadIdx.x;
    const int tot = B_ * (S_ + 2) * D_;
    if (idx >= tot) return;
    int d = idx % D_;
    int sp = (idx / D_) % (S_ + 2);
    int b = idx / (D_ * (S_ + 2));
    float v = 0.f;
    if (sp >= 1 && sp <= S_) {
        int tok = text[b * S_ + sp - 1];
        v = embed[(long)tok * D_ + d];
    }
    ushort h, l, q; split3(v, h, l, q);
    xpH[idx] = h; xpL[idx] = l; xpQ[idx] = q;
}

// conv_w [o][i][w] -> cwT [o][w*D+i]  (B^T layout), 3 planes
__global__ __launch_bounds__(256) void repack_conv_k(const float* __restrict__ w,
                                                     ushort* __restrict__ cH,
                                                     ushort* __restrict__ cL,
                                                     ushort* __restrict__ cQ) {
    int idx = blockIdx.x * 256 + threadIdx.x;
    if (idx >= D_ * 3 * D_) return;
    int o = idx / (3 * D_);
    int r = idx % (3 * D_);
    int wi = r / D_;
    int i = r % D_;
    float v = w[((long)o * D_ + i) * 3 + wi];
    ushort h, l, q; split3(v, h, l, q);
    cH[idx] = h; cL[idx] = l; cQ[idx] = q;
}

__global__ __launch_bounds__(256) void conv_rows_k(int* __restrict__ r) {
    int t = blockIdx.x * 256 + threadIdx.x;
    if (t < T_) r[t] = t + 2 * (t / S_);
}

__global__ void zero_cnt_k(int* c) { if (threadIdx.x < L_ * E_) c[threadIdx.x] = 0; }

__global__ void concat3_k(const float* __restrict__ a, const float* __restrict__ b,
                          const float* __restrict__ c, float* __restrict__ o) {
    int t = blockIdx.x * 256 + threadIdx.x;
    if (t < D_) o[t] = a[t];
    else if (t < 2 * D_) o[t] = b[t - D_];
    else if (t < 3 * D_) o[t] = c[t - 2 * D_];
}

// ---------------- tiled transpose + exact 3-way split: src fp32 [K][N] -> dst bf16 [N][K] ----------------
__global__ __launch_bounds__(256) void tr4_split_k(const float* __restrict__ s0,
                                                   const float* __restrict__ s1,
                                                   const float* __restrict__ s2,
                                                   const float* __restrict__ s3,
                                                   ushort* __restrict__ dH,
                                                   ushort* __restrict__ dL,
                                                   ushort* __restrict__ dQ,
                                                   int K, int N, long dstStride) {
    int z = blockIdx.z;
    const float* src = (z == 0) ? s0 : (z == 1) ? s1 : (z == 2) ? s2 : s3;
    dH += (long)z * dstStride;
    dL += (long)z * dstStride;
    dQ += (long)z * dstStride;
    __shared__ float tile[32][33];
    int tx = threadIdx.x & 31, ty = threadIdx.x >> 5;
    int n = blockIdx.x * 32 + tx;
    int k0 = blockIdx.y * 32;
    #pragma unroll
    for (int r = ty; r < 32; r += 8)
        tile[r][tx] = src[(long)(k0 + r) * N + n];
    __syncthreads();
    int k = k0 + tx;
    long nb = (long)blockIdx.x * 32;
    #pragma unroll
    for (int r = ty; r < 32; r += 8) {
        float v = tile[tx][r];
        ushort h, l, q; split3(v, h, l, q);
        dH[(nb + r) * K + k] = h;
        dL[(nb + r) * K + k] = l;
        dQ[(nb + r) * K + k] = q;
    }
}

// ---------------- LayerNorm: fp32 in, exact 3-plane bf16 out ----------------
__global__ __launch_bounds__(256) void ln_k(const float* __restrict__ x,
                                            const float* __restrict__ g,
                                            const float* __restrict__ bb,
                                            ushort* __restrict__ oH,
                                            ushort* __restrict__ oL,
                                            ushort* __restrict__ oQ) {
    __shared__ float red[256];
    int row = blockIdx.x, tid = threadIdx.x;
    const float* xr = x + (long)row * D_;
    float v0 = xr[tid], v1 = xr[tid + 256], v2 = xr[tid + 512];
    red[tid] = v0 + v1 + v2; __syncthreads();
    for (int off = 128; off; off >>= 1) { if (tid < off) red[tid] += red[tid + off]; __syncthreads(); }
    float mean = red[0] * (1.f / D_);
    __syncthreads();
    float d0 = v0 - mean, d1 = v1 - mean, d2 = v2 - mean;
    red[tid] = d0 * d0 + d1 * d1 + d2 * d2; __syncthreads();
    for (int off = 128; off; off >>= 1) { if (tid < off) red[tid] += red[tid + off]; __syncthreads(); }
    float rs = rsqrtf(red[0] * (1.f / D_) + 1e-5f);
    long base = (long)row * D_;
    float y0 = d0 * rs * g[tid]       + bb[tid];
    float y1 = d1 * rs * g[tid + 256] + bb[tid + 256];
    float y2 = d2 * rs * g[tid + 512] + bb[tid + 512];
    ushort h, l, q;
    split3(y0, h, l, q); oH[base + tid]       = h; oL[base + tid]       = l; oQ[base + tid]       = q;
    split3(y1, h, l, q); oH[base + tid + 256] = h; oL[base + tid + 256] = l; oQ[base + tid + 256] = q;
    split3(y2, h, l, q); oH[base + tid + 512] = h; oL[base + tid + 512] = l; oQ[base + tid + 512] = q;
}

// ---------------- bf16x6 MFMA GEMM (fp32-exact class) ----------------
// C = A*B with A,B exactly split into hi/lo/llo bf16 planes; 6 terms:
// hh + hl + lh + ll + h*q + q*h  -> residual ~2^-27, below fp32 FMA rounding.
// Tile 128x128, 4 waves (2x2) of 64x64, mfma_f32_16x16x32_bf16, direct global loads.
__global__ __launch_bounds__(256) void mfma_gemm_k(
    const ushort* __restrict__ AH, const ushort* __restrict__ AL, const ushort* __restrict__ AQ,
    const ushort* __restrict__ BH, const ushort* __restrict__ BL, const ushort* __restrict__ BQ,
    const float* __restrict__ bias,
    const float* __restrict__ resid,
    const ushort* __restrict__ rH, const ushort* __restrict__ rL, const ushort* __restrict__ rQ,
    float* __restrict__ C, ushort* __restrict__ CH, ushort* __restrict__ CL, ushort* __restrict__ CQ,
    const int* __restrict__ a_rows, const int* __restrict__ res_rows,
    const int* __restrict__ m_ptr,
    int M, int N, int K, int lda, int ldc, int act,
    const int* __restrict__ scat_rows, const float* __restrict__ scat_scale)
{
    int Meff = m_ptr ? *m_ptr : M;
    int m0 = blockIdx.y * 128, n0 = blockIdx.x * 128;
    if (m0 >= Meff) return;
    int Kc = K / gridDim.z;
    int kbeg = blockIdx.z * Kc;
    int kend = kbeg + Kc;

    int lane = threadIdx.x & 63;
    int wave = threadIdx.x >> 6;
    int wm = wave >> 1, wn = wave & 1;
    int lr = lane & 15;          // frag row (A) / col (B/C)
    int g  = lane >> 4;          // k-group

    long aoff[4];
    #pragma unroll
    for (int m = 0; m < 4; ++m) {
        int grow = m0 + wm * 64 + m * 16 + lr;
        int gr = grow < Meff ? grow : (Meff - 1);   // clamp: garbage rows discarded at store
        int r = a_rows ? a_rows[gr] : gr;
        aoff[m] = (long)r * lda + g * 8;
    }
    long boff[4];
    #pragma unroll
    for (int n = 0; n < 4; ++n) {
        int bcol = n0 + wn * 64 + n * 16 + lr;
        boff[n] = (long)bcol * K + g * 8;
    }

    f32x4 acc[4][4];
    #pragma unroll
    for (int m = 0; m < 4; ++m)
        #pragma unroll
        for (int n = 0; n < 4; ++n)
            acc[m][n] = (f32x4){0.f, 0.f, 0.f, 0.f};

    for (int k0 = kbeg; k0 < kend; k0 += 32) {
        bf16x8 ah[4], al[4], aq[4];
        #pragma unroll
        for (int m = 0; m < 4; ++m) {
            ah[m] = *reinterpret_cast<const bf16x8*>(AH + aoff[m] + k0);
            al[m] = *reinterpret_cast<const bf16x8*>(AL + aoff[m] + k0);
            aq[m] = *reinterpret_cast<const bf16x8*>(AQ + aoff[m] + k0);
        }
        #pragma unroll
        for (int n = 0; n < 4; ++n) {
            bf16x8 bh = *reinterpret_cast<const bf16x8*>(BH + boff[n] + k0);
            bf16x8 bl = *reinterpret_cast<const bf16x8*>(BL + boff[n] + k0);
            bf16x8 bq = *reinterpret_cast<const bf16x8*>(BQ + boff[n] + k0);
            #pragma unroll
            for (int m = 0; m < 4; ++m) {
                acc[m][n] = __builtin_amdgcn_mfma_f32_16x16x32_bf16(ah[m], bh, acc[m][n], 0, 0, 0);
                acc[m][n] = __builtin_amdgcn_mfma_f32_16x16x32_bf16(ah[m], bl, acc[m][n], 0, 0, 0);
                acc[m][n] = __builtin_amdgcn_mfma_f32_16x16x32_bf16(al[m], bh, acc[m][n], 0, 0, 0);
                acc[m][n] = __builtin_amdgcn_mfma_f32_16x16x32_bf16(al[m], bl, acc[m][n], 0, 0, 0);
                acc[m][n] = __builtin_amdgcn_mfma_f32_16x16x32_bf16(ah[m], bq, acc[m][n], 0, 0, 0);
                acc[m][n] = __builtin_amdgcn_mfma_f32_16x16x32_bf16(aq[m], bh, acc[m][n], 0, 0, 0);
            }
        }
    }

    // epilogue: C/D layout col=lane&15, row=(lane>>4)*4+reg
    #pragma unroll
    for (int m = 0; m < 4; ++m) {
        #pragma unroll
        for (int rr = 0; rr < 4; ++rr) {
            int row = m0 + wm * 64 + m * 16 + g * 4 + rr;
            if (row >= Meff) continue;
            #pragma unroll
            for (int n = 0; n < 4; ++n) {
                int col = n0 + wn * 64 + n * 16 + lr;
                float v = acc[m][n][rr];
                if (bias && blockIdx.z == 0) v += bias[col];
                if (act == 1) v = gelu_f(v);
                if (scat_rows) {
                    int t = scat_rows[row];
                    atomicAdd(&C[(long)t * ldc + col], scat_scale[row] * v);
                } else {
                    if (resid) {
                        int rq = res_rows ? res_rows[row] : row;
                        v += resid[(long)rq * ldc + col];
                    } else if (rH) {
                        int rq = res_rows ? res_rows[row] : row;
                        long off = (long)rq * ldc + col;
                        v += bf2f(rH[off]) + bf2f(rL[off]) + bf2f(rQ[off]);  // exact reconstruction
                    }
                    if (CH) {
                        long off = (long)row * ldc + col;
                        ushort hh, ll, qq; split3(v, hh, ll, qq);
                        CH[off] = hh; CL[off] = ll; CQ[off] = qq;
                    } else {
                        C[(long)row * ldc + col] = v;
                    }
                }
            }
        }
    }
}

// ---------------- flash attention (fp32 math): fused QKV input, 3-plane bf16 output ----------------
#define FA_PAD 68
__global__ __launch_bounds__(256) void flash_attn_k(const float* __restrict__ QKV,
                                                    ushort* __restrict__ OH,
                                                    ushort* __restrict__ OL,
                                                    ushort* __restrict__ OQ) {
    __shared__ float Qt[64][FA_PAD];
    __shared__ float KP[64][FA_PAD];
    __shared__ float Vs[64][FA_PAD];
    int blk = blockIdx.x;
    int qt = blk & 15;                  // S_/64 = 16
    int h  = (blk >> 4) % H_;
    int b  = blk / (16 * H_);
    int q0 = qt * 64;
    long baseq = ((long)b * S_) * QKV_LD + h * DH_;
    int tid = threadIdx.x;
    int tx = tid & 15, ty = tid >> 4;
    int j = tid >> 2, c0 = (tid & 3) * 16;

    {
        const float* qp = QKV + baseq + (long)(q0 + j) * QKV_LD + c0;
        #pragma unroll
        for (int m = 0; m < 16; m += 4) {
            float4 v = *(const float4*)(qp + m);
            Qt[c0 + m + 0][j] = v.x; Qt[c0 + m + 1][j] = v.y;
            Qt[c0 + m + 2][j] = v.z; Qt[c0 + m + 3][j] = v.w;
        }
    }
    float o[4][4] = {};
    float mprev[4] = {-1e30f, -1e30f, -1e30f, -1e30f};
    float l[4] = {0.f, 0.f, 0.f, 0.f};

    for (int k0 = 0; k0 < S_; k0 += 64) {
        __syncthreads();
        {
            const float* kp = QKV + baseq + D_ + (long)(k0 + j) * QKV_LD + c0;
            #pragma unroll
            for (int m = 0; m < 16; m += 4) {
                float4 v = *(const float4*)(kp + m);
                KP[c0 + m + 0][j] = v.x; KP[c0 + m + 1][j] = v.y;
                KP[c0 + m + 2][j] = v.z; KP[c0 + m + 3][j] = v.w;
            }
            const float* vp = QKV + baseq + 2 * D_ + (long)(k0 + j) * QKV_LD + c0;
            #pragma unroll
            for (int m = 0; m < 16; m += 4) {
                *(float4*)&Vs[j][c0 + m] = *(const float4*)(vp + m);
            }
        }
        __syncthreads();
        float s[4][4] = {};
        #pragma unroll 8
        for (int d = 0; d < 64; ++d) {
            float4 qv = *(float4*)&Qt[d][ty * 4];
            float4 kv = *(float4*)&KP[d][tx * 4];
            s[0][0] += qv.x * kv.x; s[0][1] += qv.x * kv.y; s[0][2] += qv.x * kv.z; s[0][3] += qv.x * kv.w;
            s[1][0] += qv.y * kv.x; s[1][1] += qv.y * kv.y; s[1][2] += qv.y * kv.z; s[1][3] += qv.y * kv.w;
            s[2][0] += qv.z * kv.x; s[2][1] += qv.z * kv.y; s[2][2] += qv.z * kv.z; s[2][3] += qv.z * kv.w;
            s[3][0] += qv.w * kv.x; s[3][1] += qv.w * kv.y; s[3][2] += qv.w * kv.z; s[3][3] += qv.w * kv.w;
        }
        float alpha[4];
        #pragma unroll
        for (int i = 0; i < 4; ++i) {
            s[i][0] *= 0.125f; s[i][1] *= 0.125f; s[i][2] *= 0.125f; s[i][3] *= 0.125f;
            float mloc = fmaxf(fmaxf(s[i][0], s[i][1]), fmaxf(s[i][2], s[i][3]));
            #pragma unroll
            for (int off = 1; off < 16; off <<= 1) mloc = fmaxf(mloc, __shfl_xor(mloc, off));
            float mnew = fmaxf(mprev[i], mloc);
            alpha[i] = __expf(mprev[i] - mnew);
            s[i][0] = __expf(s[i][0] - mnew); s[i][1] = __expf(s[i][1] - mnew);
            s[i][2] = __expf(s[i][2] - mnew); s[i][3] = __expf(s[i][3] - mnew);
            float rs = s[i][0] + s[i][1] + s[i][2] + s[i][3];
            #pragma unroll
            for (int off = 1; off < 16; off <<= 1) rs += __shfl_xor(rs, off);
            l[i] = l[i] * alpha[i] + rs;
            mprev[i] = mnew;
            o[i][0] *= alpha[i]; o[i][1] *= alpha[i]; o[i][2] *= alpha[i]; o[i][3] *= alpha[i];
        }
        __syncthreads();
        #pragma unroll
        for (int i = 0; i < 4; ++i)
            *(float4*)&KP[ty * 4 + i][tx * 4] = make_float4(s[i][0], s[i][1], s[i][2], s[i][3]);
        __syncthreads();
        #pragma unroll 4
        for (int kk = 0; kk < 64; kk += 4) {
            float4 pr[4];
            #pragma unroll
            for (int i = 0; i < 4; ++i) pr[i] = *(float4*)&KP[ty * 4 + i][kk];
            #pragma unroll
            for (int e = 0; e < 4; ++e) {
                float4 vv = *(float4*)&Vs[kk + e][tx * 4];
                float pe0 = e == 0 ? pr[0].x : e == 1 ? pr[0].y : e == 2 ? pr[0].z : pr[0].w;
                float pe1 = e == 0 ? pr[1].x : e == 1 ? pr[1].y : e == 2 ? pr[1].z : pr[1].w;
                float pe2 = e == 0 ? pr[2].x : e == 1 ? pr[2].y : e == 2 ? pr[2].z : pr[2].w;
                float pe3 = e == 0 ? pr[3].x : e == 1 ? pr[3].y : e == 2 ? pr[3].z : pr[3].w;
                o[0][0] += pe0 * vv.x; o[0][1] += pe0 * vv.y; o[0][2] += pe0 * vv.z; o[0][3] += pe0 * vv.w;
                o[1][0] += pe1 * vv.x; o[1][1] += pe1 * vv.y; o[1][2] += pe1 * vv.z; o[1][3] += pe1 * vv.w;
                o[2][0] += pe2 * vv.x; o[2][1] += pe2 * vv.y; o[2][2] += pe2 * vv.z; o[2][3] += pe2 * vv.w;
                o[3][0] += pe3 * vv.x; o[3][1] += pe3 * vv.y; o[3][2] += pe3 * vv.z; o[3][3] += pe3 * vv.w;
            }
        }
    }
    long baseo = ((long)b * S_) * D_ + h * DH_;
    #pragma unroll
    for (int i = 0; i < 4; ++i) {
        float inv = 1.f / l[i];
        ushort4 hv, lv, qv;
        float v0 = o[i][0] * inv, v1 = o[i][1] * inv, v2 = o[i][2] * inv, v3 = o[i][3] * inv;
        split3(v0, hv.x, lv.x, qv.x);
        split3(v1, hv.y, lv.y, qv.y);
        split3(v2, hv.z, lv.z, qv.z);
        split3(v3, hv.w, lv.w, qv.w);
        long off = baseo + (long)(q0 + ty * 4 + i) * D_ + tx * 4;
        *(ushort4*)(OH + off) = hv;
        *(ushort4*)(OL + off) = lv;
        *(ushort4*)(OQ + off) = qv;
    }
}

// ---------------- fused router: logits (exact fp32 via h+l+q) + softmax + top2 + scatter lists ----------------
__global__ __launch_bounds__(256) void router_fused_k(const ushort* __restrict__ HH,
                                                      const ushort* __restrict__ HL,
                                                      const ushort* __restrict__ HQ,
                                                      const float* __restrict__ rw,
                                                      const float* __restrict__ rb,
                                                      int* __restrict__ cnt,
                                                      int* __restrict__ list,
                                                      float* __restrict__ gate_slot) {
    __shared__ float rws[D_ * E_];
    int tid = threadIdx.x;
    for (int idx = tid; idx < D_ * E_; idx += 256) rws[idx] = rw[idx];
    __syncthreads();
    int tok = blockIdx.x * 64 + (tid >> 2);
    int e = tid & 3;
    const ushort* hh = HH + (long)tok * D_;
    const ushort* hl = HL + (long)tok * D_;
    const ushort* hq = HQ + (long)tok * D_;
    float s = rb[e];
    for (int d0 = 0; d0 < D_; d0 += 8) {
        u16x8 vh = *reinterpret_cast<const u16x8*>(hh + d0);
        u16x8 vl = *reinterpret_cast<const u16x8*>(hl + d0);
        u16x8 vq = *reinterpret_cast<const u16x8*>(hq + d0);
        #pragma unroll
        for (int jj = 0; jj < 8; ++jj) {
            float hv = bf2f((ushort)vh[jj]) + bf2f((ushort)vl[jj]) + bf2f((ushort)vq[jj]);
            s += hv * rws[(d0 + jj) * E_ + e];
        }
    }
    int lane = tid & 63;
    int bl = lane & ~3;
    float l0 = __shfl(s, bl + 0), l1 = __shfl(s, bl + 1);
    float l2 = __shfl(s, bl + 2), l3 = __shfl(s, bl + 3);
    if (e == 0) {
        float m = fmaxf(fmaxf(l0, l1), fmaxf(l2, l3));
        float p[4] = { __expf(l0 - m), __expf(l1 - m), __expf(l2 - m), __expf(l3 - m) };
        int i0 = 0; float v0p = p[0];
        #pragma unroll
        for (int q = 1; q < 4; ++q) if (p[q] > v0p) { v0p = p[q]; i0 = q; }
        int i1 = -1; float v1p = -1.f;
        #pragma unroll
        for (int q = 0; q < 4; ++q) { if (q == i0) continue; if (p[q] > v1p) { v1p = p[q]; i1 = q; } }
        float g0 = v0p / (v0p + v1p), g1 = v1p / (v0p + v1p);
        int pos0 = atomicAdd(&cnt[i0], 1);
        list[i0 * T_ + pos0] = tok; gate_slot[i0 * T_ + pos0] = g0;
        int pos1 = atomicAdd(&cnt[i1], 1);
        list[i1 * T_ + pos1] = tok; gate_slot[i1 * T_ + pos1] = g1;
    }
}

extern "C" void kernel_launch(void* const* d_in, const int* in_sizes, int n_in,
                              void* d_out, int out_size, void* d_ws, size_t ws_size,
                              hipStream_t stream) {
    const int*   text   = (const int*)  d_in[0];
    const float* embed  = (const float*)d_in[1];
    const float* conv_w = (const float*)d_in[2];
    const float* conv_b = (const float*)d_in[3];
    const float* Wq = (const float*)d_in[4],  *bq = (const float*)d_in[5];
    const float* Wk = (const float*)d_in[6],  *bk = (const float*)d_in[7];
    const float* Wv = (const float*)d_in[8],  *bv = (const float*)d_in[9];
    const float* Wo = (const float*)d_in[10], *bo = (const float*)d_in[11];
    const float* rw = (const float*)d_in[12], *rb = (const float*)d_in[13];
    const float* ew1 = (const float*)d_in[14], *eb1 = (const float*)d_in[15];
    const float* ew2 = (const float*)d_in[16], *eb2 = (const float*)d_in[17];
    const float* ln1g = (const float*)d_in[18], *ln1b = (const float*)d_in[19];
    const float* ln2g = (const float*)d_in[20], *ln2b = (const float*)d_in[21];
    const float* lnfg = (const float*)d_in[22], *lnfb = (const float*)d_in[23];
    const float* outw = (const float*)d_in[24], *outb = (const float*)d_in[25];
    float* out = (float*)d_out;
    (void)ws_size; (void)in_sizes; (void)n_in; (void)out_size;

    // ---- workspace layout (floats). BIG region is time-multiplexed:
    //   phase conv : xp planes [0, 4.73M) + cwT planes [4.73M, 7.38M)
    //   phase attn : qkv fp32 [0, 9.44M) ; ob planes [9.44M, 14.16M) ; wT4 planes [14.16M, 17.69M)
    //   phase moe  : h1 planes [0, 18.87M)
    //   phase head : owT planes [0, 0.30M)
    const size_t XP = (size_t)B_ * (S_ + 2) * D_;   // 3,151,872 ushorts per plane
    const size_t TD = (size_t)T_ * D_;              // 3,145,728
    const size_t TF = (size_t)T_ * F_;              // 12,582,912
    const size_t W4 = (size_t)4 * D_ * D_;          // 2,359,296
    const size_t CW = (size_t)D_ * 3 * D_;          // 1,769,472
    const size_t VD = (size_t)V_ * D_;              // 196,608
    const size_t DF = (size_t)D_ * F_;              // 2,359,296
    const size_t BIG_FL = 3 * TF / 2;               // 18,874,368 floats

    float* BIGf = (float*)d_ws;
    ushort* BIGu = (ushort*)BIGf;
    ushort* xpH = BIGu;            ushort* xpL = xpH + XP;  ushort* xpQ = xpL + XP;
    ushort* cwH = BIGu + 3 * XP;   ushort* cwL = cwH + CW;  ushort* cwQ = cwL + CW;
    float*  qkv = BIGf;                                     // 9,437,184 floats
    ushort* obH = BIGu + 2 * ((size_t)T_ * 3 * D_) / 2 * 0 + 18874368; // = BIGu + 18,874,368
    ushort* obL = obH + TD;        ushort* obQ = obL + TD;
    ushort* w4H = BIGu + 28311552; ushort* w4L = w4H + W4;  ushort* w4Q = w4L + W4;
    ushort* owH = BIGu;            ushort* owL = owH + VD;  ushort* owQ = owL + VD;
    ushort* h1H = BIGu;            ushort* h1L = h1H + TF;  ushort* h1Q = h1L + TF;

    float* x     = BIGf + BIG_FL;                  // 3,145,728
    ushort* hH   = (ushort*)(x + TD);              // 3 planes T*D
    ushort* hL   = hH + TD;
    ushort* hQ   = hL + TD;
    float* e1base = x + TD + 3 * TD / 2;           // 3 planes D*F
    ushort* e1H = (ushort*)e1base; ushort* e1L = e1H + DF; ushort* e1Q = e1L + DF;
    float* e2base = e1base + 3 * DF / 2;
    ushort* e2H = (ushort*)e2base; ushort* e2L = e2H + DF; ushort* e2Q = e2L + DF;
    float* qkvb = e2base + 3 * DF / 2;             // 2304
    int* conv_rows = (int*)(qkvb + 3 * D_);        // 4096
    int* list      = conv_rows + T_;               // 16384
    float* gate_slot = (float*)(list + E_ * T_);   // 16384
    int* cnt       = (int*)(gate_slot + E_ * T_);  // 16

    zero_cnt_k<<<1, 64, 0, stream>>>(cnt);
    embed_pad_k<<<(B_ * (S_ + 2) * D_ + 255) / 256, 256, 0, stream>>>(text, embed, xpH, xpL, xpQ);
    repack_conv_k<<<(3 * D_ * D_ + 255) / 256, 256, 0, stream>>>(conv_w, cwH, cwL, cwQ);
    conv_rows_k<<<(T_ + 255) / 256, 256, 0, stream>>>(conv_rows);
    // conv-as-GEMM: x = gelu(xpad*cw + conv_b) + center-token embedding (exact 3-plane resid)
    mfma_gemm_k<<<dim3(D_ / 128, T_ / 128, 1), 256, 0, stream>>>(
        xpH, xpL, xpQ, cwH, cwL, cwQ, conv_b, nullptr,
        xpH + D_, xpL + D_, xpQ + D_,
        x, nullptr, nullptr, nullptr,
        conv_rows, conv_rows, nullptr, T_, D_, 3 * D_, D_, D_, 1, nullptr, nullptr);

    const long DD = (long)D_ * D_;
    for (int i = 0; i < L_; ++i) {
        ln_k<<<T_, 256, 0, stream>>>(x, ln1g + i * D_, ln1b + i * D_, hH, hL, hQ);
        tr4_split_k<<<dim3(D_ / 32, D_ / 32, 4), 256, 0, stream>>>(
            Wq + i * DD, Wk + i * DD, Wv + i * DD, Wo + i * DD, w4H, w4L, w4Q, D_, D_, DD);
        concat3_k<<<9, 256, 0, stream>>>(bq + i * D_, bk + i * D_, bv + i * D_, qkvb);
        // fused QKV: [T][2304] fp32
        mfma_gemm_k<<<dim3(3 * D_ / 128, T_ / 128, 1), 256, 0, stream>>>(
            hH, hL, hQ, w4H, w4L, w4Q, qkvb, nullptr, nullptr, nullptr, nullptr,
            qkv, nullptr, nullptr, nullptr,
            nullptr, nullptr, nullptr, T_, 3 * D_, D_, D_, 3 * D_, 0, nullptr, nullptr);
        flash_attn_k<<<B_ * H_ * (S_ / 64), 256, 0, stream>>>(qkv, obH, obL, obQ);
        mfma_gemm_k<<<dim3(D_ / 128, T_ / 128, 1), 256, 0, stream>>>(
            obH, obL, obQ, w4H + 3 * W4 / 4 * 0 + 3 * DD, w4L + 3 * DD, w4Q + 3 * DD,
            bo + i * D_, x, nullptr, nullptr, nullptr,
            x, nullptr, nullptr, nullptr,
            nullptr, nullptr, nullptr, T_, D_, D_, D_, D_, 0, nullptr, nullptr);
        ln_k<<<T_, 256, 0, stream>>>(x, ln2g + i * D_, ln2b + i * D_, hH, hL, hQ);
        router_fused_k<<<T_ / 64, 256, 0, stream>>>(
            hH, hL, hQ, rw + (long)i * D_ * E_, rb + i * E_, cnt + i * E_, list, gate_slot);
        for (int e = 0; e < E_; ++e) {
            const float* w1 = ew1 + ((long)i * E_ + e) * D_ * F_;
            const float* w2 = ew2 + ((long)i * E_ + e) * F_ * D_;
            tr4_split_k<<<dim3(F_ / 32, D_ / 32, 1), 256, 0, stream>>>(
                w1, w1, w1, w1, e1H, e1L, e1Q, D_, F_, 0);
            mfma_gemm_k<<<dim3(F_ / 128, T_ / 128, 1), 256, 0, stream>>>(
                hH, hL, hQ, e1H, e1L, e1Q, eb1 + ((long)i * E_ + e) * F_, nullptr, nullptr, nullptr, nullptr,
                nullptr, h1H, h1L, h1Q,
                list + e * T_, nullptr, cnt + i * E_ + e, T_, F_, D_, D_, F_, 1, nullptr, nullptr);
            tr4_split_k<<<dim3(D_ / 32, F_ / 32, 1), 256, 0, stream>>>(
                w2, w2, w2, w2, e2H, e2L, e2Q, F_, D_, 0);
            // K-split z=4 (exact: output is atomic scatter; bias only from z==0)
            mfma_gemm_k<<<dim3(D_ / 128, T_ / 128, 4), 256, 0, stream>>>(
                h1H, h1L, h1Q, e2H, e2L, e2Q, eb2 + ((long)i * E_ + e) * D_, nullptr, nullptr, nullptr, nullptr,
                x, nullptr, nullptr, nullptr,
                nullptr, nullptr, cnt + i * E_ + e, T_, D_, F_, F_, D_, 0,
                list + e * T_, gate_slot + e * T_);
        }
    }
    ln_k<<<T_, 256, 0, stream>>>(x, lnfg, lnfb, hH, hL, hQ);
    tr4_split_k<<<dim3(V_ / 32, D_ / 32, 1), 256, 0, stream>>>(
        outw, outw, outw, outw, owH, owL, owQ, D_, V_, 0);
    mfma_gemm_k<<<dim3(V_ / 128, T_ / 128, 1), 256, 0, stream>>>(
        hH, hL, hQ, owH, owL, owQ, outb, nullptr, nullptr, nullptr, nullptr,
        out, nullptr, nullptr, nullptr,
        nullptr, nullptr, nullptr, T_, V_, D_, D_, V_, 0, nullptr, nullptr);
}

// Round 3
// 7890.411 us; speedup vs baseline: 1.5814x; 1.1651x over previous
//
#include <hip/hip_runtime.h>
#include <math.h>

#define L_ 4
#define B_ 4
#define S_ 1024
#define D_ 768
#define F_ 3072
#define E_ 4
#define V_ 256
#define H_ 12
#define DH_ 64
#define T_ (B_*S_)
#define QKV_LD (3*D_)

typedef __attribute__((ext_vector_type(8))) _Float16 f16x8;
typedef __attribute__((ext_vector_type(4))) float f32x4;
typedef __attribute__((ext_vector_type(8))) unsigned short u16x8;

// fp16 2-plane split: v ~= h + l/2048, error <= 2^-23|v|  (l stored x2048)
__device__ __forceinline__ void split2(float v, ushort& h, ushort& l) {
    _Float16 hh = (_Float16)v;                 // RTN
    float r = (v - (float)hh) * 2048.0f;       // exact
    _Float16 ll = (_Float16)r;
    union { _Float16 x; ushort u; } a, b; a.x = hh; b.x = ll;
    h = a.u; l = b.u;
}
__device__ __forceinline__ float h2f(ushort u) {
    union { _Float16 x; ushort u; } c; c.u = u; return (float)c.x;
}

__device__ __forceinline__ float gelu_f(float x) {
    return 0.5f * x * (1.f + tanhf(0.7978845608028654f * (x + 0.044715f * x * x * x)));
}

// ---------------- embedding lookup into padded fp16 2-plane buffers [B][S+2][D], scaled x64 ----------------
__global__ __launch_bounds__(256) void embed_pad_k(const int* __restrict__ text,
                                                   const float* __restrict__ embed,
                                                   ushort* __restrict__ xpH,
                                                   ushort* __restrict__ xpL) {
    int idx = blockIdx.x * 256 + threadIdx.x;
    const int tot = B_ * (S_ + 2) * D_;
    if (idx >= tot) return;
    int d = idx % D_;
    int sp = (idx / D_) % (S_ + 2);
    int b = idx / (D_ * (S_ + 2));
    float v = 0.f;
    if (sp >= 1 && sp <= S_) {
        int tok = text[b * S_ + sp - 1];
        v = embed[(long)tok * D_ + d];
    }
    ushort h, l; split2(v * 64.0f, h, l);
    xpH[idx] = h; xpL[idx] = l;
}

// conv_w [o][i][w] -> cwT [o][w*D+i]  (B^T layout), 2 planes, scaled x64
__global__ __launch_bounds__(256) void repack_conv_k(const float* __restrict__ w,
                                                     ushort* __restrict__ cH,
                                                     ushort* __restrict__ cL) {
    int idx = blockIdx.x * 256 + threadIdx.x;
    if (idx >= D_ * 3 * D_) return;
    int o = idx / (3 * D_);
    int r = idx % (3 * D_);
    int wi = r / D_;
    int i = r % D_;
    float v = w[((long)o * D_ + i) * 3 + wi];
    ushort h, l; split2(v * 64.0f, h, l);
    cH[idx] = h; cL[idx] = l;
}

__global__ __launch_bounds__(256) void conv_rows_k(int* __restrict__ r) {
    int t = blockIdx.x * 256 + threadIdx.x;
    if (t < T_) r[t] = t + 2 * (t / S_);
}

__global__ void zero_cnt_k(int* c) { if (threadIdx.x < L_ * E_) c[threadIdx.x] = 0; }

__global__ void concat3_k(const float* __restrict__ a, const float* __restrict__ b,
                          const float* __restrict__ c, float* __restrict__ o) {
    int t = blockIdx.x * 256 + threadIdx.x;
    if (t < D_) o[t] = a[t];
    else if (t < 2 * D_) o[t] = b[t - D_];
    else if (t < 3 * D_) o[t] = c[t - 2 * D_];
}

// ---------------- tiled transpose + fp16 2-plane split (x64): src fp32 [K][N] -> dst [N][K] ----------------
__global__ __launch_bounds__(256) void tr4_split_k(const float* __restrict__ s0,
                                                   const float* __restrict__ s1,
                                                   const float* __restrict__ s2,
                                                   const float* __restrict__ s3,
                                                   ushort* __restrict__ dH,
                                                   ushort* __restrict__ dL,
                                                   int K, int N, long dstStride) {
    int z = blockIdx.z;
    const float* src = (z == 0) ? s0 : (z == 1) ? s1 : (z == 2) ? s2 : s3;
    dH += (long)z * dstStride;
    dL += (long)z * dstStride;
    __shared__ float tile[32][33];
    int tx = threadIdx.x & 31, ty = threadIdx.x >> 5;
    int n = blockIdx.x * 32 + tx;
    int k0 = blockIdx.y * 32;
    #pragma unroll
    for (int r = ty; r < 32; r += 8)
        tile[r][tx] = src[(long)(k0 + r) * N + n];
    __syncthreads();
    int k = k0 + tx;
    long nb = (long)blockIdx.x * 32;
    #pragma unroll
    for (int r = ty; r < 32; r += 8) {
        ushort h, l; split2(tile[tx][r] * 64.0f, h, l);
        dH[(nb + r) * K + k] = h;
        dL[(nb + r) * K + k] = l;
    }
}

// ---------------- LayerNorm: fp32 in, fp16 2-plane out (unscaled) ----------------
__global__ __launch_bounds__(256) void ln_k(const float* __restrict__ x,
                                            const float* __restrict__ g,
                                            const float* __restrict__ bb,
                                            ushort* __restrict__ oH,
                                            ushort* __restrict__ oL) {
    __shared__ float red[256];
    int row = blockIdx.x, tid = threadIdx.x;
    const float* xr = x + (long)row * D_;
    float v0 = xr[tid], v1 = xr[tid + 256], v2 = xr[tid + 512];
    red[tid] = v0 + v1 + v2; __syncthreads();
    for (int off = 128; off; off >>= 1) { if (tid < off) red[tid] += red[tid + off]; __syncthreads(); }
    float mean = red[0] * (1.f / D_);
    __syncthreads();
    float d0 = v0 - mean, d1 = v1 - mean, d2 = v2 - mean;
    red[tid] = d0 * d0 + d1 * d1 + d2 * d2; __syncthreads();
    for (int off = 128; off; off >>= 1) { if (tid < off) red[tid] += red[tid + off]; __syncthreads(); }
    float rs = rsqrtf(red[0] * (1.f / D_) + 1e-5f);
    long base = (long)row * D_;
    float y0 = d0 * rs * g[tid]       + bb[tid];
    float y1 = d1 * rs * g[tid + 256] + bb[tid + 256];
    float y2 = d2 * rs * g[tid + 512] + bb[tid + 512];
    ushort h, l;
    split2(y0, h, l); oH[base + tid]       = h; oL[base + tid]       = l;
    split2(y1, h, l); oH[base + tid + 256] = h; oL[base + tid + 256] = l;
    split2(y2, h, l); oH[base + tid + 512] = h; oL[base + tid + 512] = l;
}

// ---------------- fp16x3 MFMA GEMM (fp32-class: err ~2^-22) ----------------
// A,B split into (h, l*2048) fp16 planes. acc0 = sum h*h ; acc1 = sum (h*l' + l'*h).
// result = (acc0 + acc1/2048) * invScale,  invScale = 2^-(sa+sb) for pre-scaled operands.
// Tile 128x128, 4 waves (2x2) of 64x64, mfma_f32_16x16x32_f16, direct global loads.
// Bijective XCD swizzle (column-chunked) for per-XCD L2 B-panel residency.
__global__ __launch_bounds__(256, 2) void mfma_gemm_k(
    const ushort* __restrict__ AH, const ushort* __restrict__ AL,
    const ushort* __restrict__ BH, const ushort* __restrict__ BL,
    const float* __restrict__ bias,
    const float* __restrict__ resid,
    const ushort* __restrict__ rH, const ushort* __restrict__ rL, float resInvScale,
    float* __restrict__ C, ushort* __restrict__ CH, ushort* __restrict__ CL,
    const int* __restrict__ a_rows, const int* __restrict__ res_rows,
    const int* __restrict__ m_ptr,
    int M, int N, int K, int lda, int ldc, int act, float invScale,
    const int* __restrict__ scat_rows, const float* __restrict__ scat_scale)
{
    // ---- XCD-aware bijective swizzle of the (x,y) block id ----
    int nbx = gridDim.x, nby = gridDim.y;
    int nwg = nbx * nby;
    int orig = blockIdx.y * nbx + blockIdx.x;
    int qq = nwg >> 3, rr8 = nwg & 7;
    int xcd = orig & 7, sidx = orig >> 3;
    int wg = (xcd < rr8 ? xcd * (qq + 1) : rr8 * (qq + 1) + (xcd - rr8) * qq) + sidx;
    int bx = wg / nby;        // consecutive wg within an XCD share bx -> B panel L2-resident
    int by = wg % nby;

    int Meff = m_ptr ? *m_ptr : M;
    int m0 = by * 128, n0 = bx * 128;
    if (m0 >= Meff) return;
    int Kc = K / gridDim.z;
    int kbeg = blockIdx.z * Kc;
    int kend = kbeg + Kc;

    int lane = threadIdx.x & 63;
    int wave = threadIdx.x >> 6;
    int wm = wave >> 1, wn = wave & 1;
    int lr = lane & 15;          // frag row (A) / col (B/C)
    int g  = lane >> 4;          // k-group

    long aoff[4];
    #pragma unroll
    for (int m = 0; m < 4; ++m) {
        int grow = m0 + wm * 64 + m * 16 + lr;
        int gr = grow < Meff ? grow : (Meff - 1);   // clamp: garbage rows discarded at store
        int r = a_rows ? a_rows[gr] : gr;
        aoff[m] = (long)r * lda + g * 8;
    }
    long boff[4];
    #pragma unroll
    for (int n = 0; n < 4; ++n) {
        int bcol = n0 + wn * 64 + n * 16 + lr;
        boff[n] = (long)bcol * K + g * 8;
    }

    f32x4 acc0[4][4], acc1[4][4];
    #pragma unroll
    for (int m = 0; m < 4; ++m)
        #pragma unroll
        for (int n = 0; n < 4; ++n) {
            acc0[m][n] = (f32x4){0.f, 0.f, 0.f, 0.f};
            acc1[m][n] = (f32x4){0.f, 0.f, 0.f, 0.f};
        }

    for (int k0 = kbeg; k0 < kend; k0 += 32) {
        f16x8 ah[4], al[4];
        #pragma unroll
        for (int m = 0; m < 4; ++m) {
            ah[m] = *reinterpret_cast<const f16x8*>(AH + aoff[m] + k0);
            al[m] = *reinterpret_cast<const f16x8*>(AL + aoff[m] + k0);
        }
        #pragma unroll
        for (int n = 0; n < 4; ++n) {
            f16x8 bh = *reinterpret_cast<const f16x8*>(BH + boff[n] + k0);
            f16x8 bl = *reinterpret_cast<const f16x8*>(BL + boff[n] + k0);
            #pragma unroll
            for (int m = 0; m < 4; ++m) {
                acc0[m][n] = __builtin_amdgcn_mfma_f32_16x16x32_f16(ah[m], bh, acc0[m][n], 0, 0, 0);
                acc1[m][n] = __builtin_amdgcn_mfma_f32_16x16x32_f16(ah[m], bl, acc1[m][n], 0, 0, 0);
                acc1[m][n] = __builtin_amdgcn_mfma_f32_16x16x32_f16(al[m], bh, acc1[m][n], 0, 0, 0);
            }
        }
    }

    // epilogue: C/D layout col=lane&15, row=(lane>>4)*4+reg
    #pragma unroll
    for (int m = 0; m < 4; ++m) {
        #pragma unroll
        for (int rr = 0; rr < 4; ++rr) {
            int row = m0 + wm * 64 + m * 16 + g * 4 + rr;
            if (row >= Meff) continue;
            #pragma unroll
            for (int n = 0; n < 4; ++n) {
                int col = n0 + wn * 64 + n * 16 + lr;
                float v = (acc0[m][n][rr] + acc1[m][n][rr] * (1.0f / 2048.0f)) * invScale;
                if (bias && blockIdx.z == 0) v += bias[col];
                if (act == 1) v = gelu_f(v);
                if (scat_rows) {
                    int t = scat_rows[row];
                    atomicAdd(&C[(long)t * ldc + col], scat_scale[row] * v);
                } else {
                    if (resid) {
                        int rq = res_rows ? res_rows[row] : row;
                        v += resid[(long)rq * ldc + col];
                    } else if (rH) {
                        int rq = res_rows ? res_rows[row] : row;
                        long off = (long)rq * ldc + col;
                        v += (h2f(rH[off]) + h2f(rL[off]) * (1.0f / 2048.0f)) * resInvScale;
                    }
                    if (CH) {
                        long off = (long)row * ldc + col;
                        ushort hh, ll; split2(v, hh, ll);
                        CH[off] = hh; CL[off] = ll;
                    } else {
                        C[(long)row * ldc + col] = v;
                    }
                }
            }
        }
    }
}

// ---------------- flash attention (fp32 math): fused QKV input, fp16 2-plane output ----------------
#define FA_PAD 68
__global__ __launch_bounds__(256) void flash_attn_k(const float* __restrict__ QKV,
                                                    ushort* __restrict__ OH,
                                                    ushort* __restrict__ OL) {
    __shared__ float Qt[64][FA_PAD];
    __shared__ float KP[64][FA_PAD];
    __shared__ float Vs[64][FA_PAD];
    int blk = blockIdx.x;
    int qt = blk & 15;                  // S_/64 = 16
    int h  = (blk >> 4) % H_;
    int b  = blk / (16 * H_);
    int q0 = qt * 64;
    long baseq = ((long)b * S_) * QKV_LD + h * DH_;
    int tid = threadIdx.x;
    int tx = tid & 15, ty = tid >> 4;
    int j = tid >> 2, c0 = (tid & 3) * 16;

    {
        const float* qp = QKV + baseq + (long)(q0 + j) * QKV_LD + c0;
        #pragma unroll
        for (int m = 0; m < 16; m += 4) {
            float4 v = *(const float4*)(qp + m);
            Qt[c0 + m + 0][j] = v.x; Qt[c0 + m + 1][j] = v.y;
            Qt[c0 + m + 2][j] = v.z; Qt[c0 + m + 3][j] = v.w;
        }
    }
    float o[4][4] = {};
    float mprev[4] = {-1e30f, -1e30f, -1e30f, -1e30f};
    float l[4] = {0.f, 0.f, 0.f, 0.f};

    for (int k0 = 0; k0 < S_; k0 += 64) {
        __syncthreads();
        {
            const float* kp = QKV + baseq + D_ + (long)(k0 + j) * QKV_LD + c0;
            #pragma unroll
            for (int m = 0; m < 16; m += 4) {
                float4 v = *(const float4*)(kp + m);
                KP[c0 + m + 0][j] = v.x; KP[c0 + m + 1][j] = v.y;
                KP[c0 + m + 2][j] = v.z; KP[c0 + m + 3][j] = v.w;
            }
            const float* vp = QKV + baseq + 2 * D_ + (long)(k0 + j) * QKV_LD + c0;
            #pragma unroll
            for (int m = 0; m < 16; m += 4) {
                *(float4*)&Vs[j][c0 + m] = *(const float4*)(vp + m);
            }
        }
        __syncthreads();
        float s[4][4] = {};
        #pragma unroll 8
        for (int d = 0; d < 64; ++d) {
            float4 qv = *(float4*)&Qt[d][ty * 4];
            float4 kv = *(float4*)&KP[d][tx * 4];
            s[0][0] += qv.x * kv.x; s[0][1] += qv.x * kv.y; s[0][2] += qv.x * kv.z; s[0][3] += qv.x * kv.w;
            s[1][0] += qv.y * kv.x; s[1][1] += qv.y * kv.y; s[1][2] += qv.y * kv.z; s[1][3] += qv.y * kv.w;
            s[2][0] += qv.z * kv.x; s[2][1] += qv.z * kv.y; s[2][2] += qv.z * kv.z; s[2][3] += qv.z * kv.w;
            s[3][0] += qv.w * kv.x; s[3][1] += qv.w * kv.y; s[3][2] += qv.w * kv.z; s[3][3] += qv.w * kv.w;
        }
        float alpha[4];
        #pragma unroll
        for (int i = 0; i < 4; ++i) {
            s[i][0] *= 0.125f; s[i][1] *= 0.125f; s[i][2] *= 0.125f; s[i][3] *= 0.125f;
            float mloc = fmaxf(fmaxf(s[i][0], s[i][1]), fmaxf(s[i][2], s[i][3]));
            #pragma unroll
            for (int off = 1; off < 16; off <<= 1) mloc = fmaxf(mloc, __shfl_xor(mloc, off));
            float mnew = fmaxf(mprev[i], mloc);
            alpha[i] = __expf(mprev[i] - mnew);
            s[i][0] = __expf(s[i][0] - mnew); s[i][1] = __expf(s[i][1] - mnew);
            s[i][2] = __expf(s[i][2] - mnew); s[i][3] = __expf(s[i][3] - mnew);
            float rs = s[i][0] + s[i][1] + s[i][2] + s[i][3];
            #pragma unroll
            for (int off = 1; off < 16; off <<= 1) rs += __shfl_xor(rs, off);
            l[i] = l[i] * alpha[i] + rs;
            mprev[i] = mnew;
            o[i][0] *= alpha[i]; o[i][1] *= alpha[i]; o[i][2] *= alpha[i]; o[i][3] *= alpha[i];
        }
        __syncthreads();
        #pragma unroll
        for (int i = 0; i < 4; ++i)
            *(float4*)&KP[ty * 4 + i][tx * 4] = make_float4(s[i][0], s[i][1], s[i][2], s[i][3]);
        __syncthreads();
        #pragma unroll 4
        for (int kk = 0; kk < 64; kk += 4) {
            float4 pr[4];
            #pragma unroll
            for (int i = 0; i < 4; ++i) pr[i] = *(float4*)&KP[ty * 4 + i][kk];
            #pragma unroll
            for (int e = 0; e < 4; ++e) {
                float4 vv = *(float4*)&Vs[kk + e][tx * 4];
                float pe0 = e == 0 ? pr[0].x : e == 1 ? pr[0].y : e == 2 ? pr[0].z : pr[0].w;
                float pe1 = e == 0 ? pr[1].x : e == 1 ? pr[1].y : e == 2 ? pr[1].z : pr[1].w;
                float pe2 = e == 0 ? pr[2].x : e == 1 ? pr[2].y : e == 2 ? pr[2].z : pr[2].w;
                float pe3 = e == 0 ? pr[3].x : e == 1 ? pr[3].y : e == 2 ? pr[3].z : pr[3].w;
                o[0][0] += pe0 * vv.x; o[0][1] += pe0 * vv.y; o[0][2] += pe0 * vv.z; o[0][3] += pe0 * vv.w;
                o[1][0] += pe1 * vv.x; o[1][1] += pe1 * vv.y; o[1][2] += pe1 * vv.z; o[1][3] += pe1 * vv.w;
                o[2][0] += pe2 * vv.x; o[2][1] += pe2 * vv.y; o[2][2] += pe2 * vv.z; o[2][3] += pe2 * vv.w;
                o[3][0] += pe3 * vv.x; o[3][1] += pe3 * vv.y; o[3][2] += pe3 * vv.z; o[3][3] += pe3 * vv.w;
            }
        }
    }
    long baseo = ((long)b * S_) * D_ + h * DH_;
    #pragma unroll
    for (int i = 0; i < 4; ++i) {
        float inv = 1.f / l[i];
        ushort4 hv, lv;
        split2(o[i][0] * inv, hv.x, lv.x);
        split2(o[i][1] * inv, hv.y, lv.y);
        split2(o[i][2] * inv, hv.z, lv.z);
        split2(o[i][3] * inv, hv.w, lv.w);
        long off = baseo + (long)(q0 + ty * 4 + i) * D_ + tx * 4;
        *(ushort4*)(OH + off) = hv;
        *(ushort4*)(OL + off) = lv;
    }
}

// ---------------- fused router: logits (fp32-class via h + l/2048) + softmax + top2 + scatter ----------------
__global__ __launch_bounds__(256) void router_fused_k(const ushort* __restrict__ HH,
                                                      const ushort* __restrict__ HL,
                                                      const float* __restrict__ rw,
                                                      const float* __restrict__ rb,
                                                      int* __restrict__ cnt,
                                                      int* __restrict__ list,
                                                      float* __restrict__ gate_slot) {
    __shared__ float rws[D_ * E_];
    int tid = threadIdx.x;
    for (int idx = tid; idx < D_ * E_; idx += 256) rws[idx] = rw[idx];
    __syncthreads();
    int tok = blockIdx.x * 64 + (tid >> 2);
    int e = tid & 3;
    const ushort* hh = HH + (long)tok * D_;
    const ushort* hl = HL + (long)tok * D_;
    float s = rb[e];
    for (int d0 = 0; d0 < D_; d0 += 8) {
        u16x8 vh = *reinterpret_cast<const u16x8*>(hh + d0);
        u16x8 vl = *reinterpret_cast<const u16x8*>(hl + d0);
        #pragma unroll
        for (int jj = 0; jj < 8; ++jj) {
            float hv = h2f((ushort)vh[jj]) + h2f((ushort)vl[jj]) * (1.0f / 2048.0f);
            s += hv * rws[(d0 + jj) * E_ + e];
        }
    }
    int lane = tid & 63;
    int bl = lane & ~3;
    float l0 = __shfl(s, bl + 0), l1 = __shfl(s, bl + 1);
    float l2 = __shfl(s, bl + 2), l3 = __shfl(s, bl + 3);
    if (e == 0) {
        float m = fmaxf(fmaxf(l0, l1), fmaxf(l2, l3));
        float p[4] = { __expf(l0 - m), __expf(l1 - m), __expf(l2 - m), __expf(l3 - m) };
        int i0 = 0; float v0p = p[0];
        #pragma unroll
        for (int q = 1; q < 4; ++q) if (p[q] > v0p) { v0p = p[q]; i0 = q; }
        int i1 = -1; float v1p = -1.f;
        #pragma unroll
        for (int q = 0; q < 4; ++q) { if (q == i0) continue; if (p[q] > v1p) { v1p = p[q]; i1 = q; } }
        float g0 = v0p / (v0p + v1p), g1 = v1p / (v0p + v1p);
        int pos0 = atomicAdd(&cnt[i0], 1);
        list[i0 * T_ + pos0] = tok; gate_slot[i0 * T_ + pos0] = g0;
        int pos1 = atomicAdd(&cnt[i1], 1);
        list[i1 * T_ + pos1] = tok; gate_slot[i1 * T_ + pos1] = g1;
    }
}

extern "C" void kernel_launch(void* const* d_in, const int* in_sizes, int n_in,
                              void* d_out, int out_size, void* d_ws, size_t ws_size,
                              hipStream_t stream) {
    const int*   text   = (const int*)  d_in[0];
    const float* embed  = (const float*)d_in[1];
    const float* conv_w = (const float*)d_in[2];
    const float* conv_b = (const float*)d_in[3];
    const float* Wq = (const float*)d_in[4],  *bq = (const float*)d_in[5];
    const float* Wk = (const float*)d_in[6],  *bk = (const float*)d_in[7];
    const float* Wv = (const float*)d_in[8],  *bv = (const float*)d_in[9];
    const float* Wo = (const float*)d_in[10], *bo = (const float*)d_in[11];
    const float* rw = (const float*)d_in[12], *rb = (const float*)d_in[13];
    const float* ew1 = (const float*)d_in[14], *eb1 = (const float*)d_in[15];
    const float* ew2 = (const float*)d_in[16], *eb2 = (const float*)d_in[17];
    const float* ln1g = (const float*)d_in[18], *ln1b = (const float*)d_in[19];
    const float* ln2g = (const float*)d_in[20], *ln2b = (const float*)d_in[21];
    const float* lnfg = (const float*)d_in[22], *lnfb = (const float*)d_in[23];
    const float* outw = (const float*)d_in[24], *outb = (const float*)d_in[25];
    float* out = (float*)d_out;
    (void)ws_size; (void)in_sizes; (void)n_in; (void)out_size;

    const size_t XP = (size_t)B_ * (S_ + 2) * D_;   // 3,151,872 u/plane
    const size_t TD = (size_t)T_ * D_;              // 3,145,728
    const size_t TF = (size_t)T_ * F_;              // 12,582,912
    const size_t W4 = (size_t)4 * D_ * D_;          // 2,359,296
    const size_t CW = (size_t)D_ * 3 * D_;          // 1,769,472
    const size_t VD = (size_t)V_ * D_;              // 196,608
    const size_t DF = (size_t)D_ * F_;              // 2,359,296
    const size_t QKV_FL = (size_t)T_ * 3 * D_;      // 9,437,184 floats
    const size_t BIG_FL = QKV_FL + (2 * TD + 2 * W4) / 2;  // 14,942,208 floats

    // BIG region (time-multiplexed):
    //  conv: xp 2-plane [0, 2XP) + cw 2-plane [2XP, 2XP+2CW)          = 9.8M u
    //  attn: qkv fp32 [0, QKV_FL) | ob 2-plane | w4 2-plane           = 29.9M u
    //  moe : h1 2-plane [0, 2TF)                                      = 25.2M u
    //  head: ow 2-plane                                               = 0.4M u
    float* BIGf = (float*)d_ws;
    ushort* BIGu = (ushort*)BIGf;
    ushort* xpH = BIGu;               ushort* xpL = xpH + XP;
    ushort* cwH = BIGu + 2 * XP;      ushort* cwL = cwH + CW;
    float*  qkv = BIGf;
    ushort* obH = BIGu + 2 * QKV_FL;  ushort* obL = obH + TD;
    ushort* w4H = obH + 2 * TD;       ushort* w4L = w4H + W4;
    ushort* h1H = BIGu;               ushort* h1L = h1H + TF;
    ushort* owH = BIGu;               ushort* owL = owH + VD;

    float* x   = BIGf + BIG_FL;                    // TD floats
    ushort* hH = (ushort*)(x + TD);                // 2 planes = TD floats
    ushort* hL = hH + TD;
    float* aft = x + TD + TD;
    ushort* e1H = (ushort*)aft;        ushort* e1L = e1H + DF;   // DF floats
    ushort* e2H = e1H + 2 * DF;        ushort* e2L = e2H + DF;   // DF floats
    float* qkvb = aft + DF + DF;
    int* conv_rows = (int*)(qkvb + 3 * D_);
    int* list      = conv_rows + T_;
    float* gate_slot = (float*)(list + E_ * T_);
    int* cnt       = (int*)(gate_slot + E_ * T_);

    const float INV64 = 1.0f / 64.0f;
    const float INV4096 = 1.0f / 4096.0f;

    zero_cnt_k<<<1, 64, 0, stream>>>(cnt);
    embed_pad_k<<<(B_ * (S_ + 2) * D_ + 255) / 256, 256, 0, stream>>>(text, embed, xpH, xpL);
    repack_conv_k<<<(3 * D_ * D_ + 255) / 256, 256, 0, stream>>>(conv_w, cwH, cwL);
    conv_rows_k<<<(T_ + 255) / 256, 256, 0, stream>>>(conv_rows);
    // conv-as-GEMM: x = gelu(xpad*cw + conv_b) + center-token embedding (2-plane resid, x64)
    mfma_gemm_k<<<dim3(D_ / 128, T_ / 128, 1), 256, 0, stream>>>(
        xpH, xpL, cwH, cwL, conv_b, nullptr,
        xpH + D_, xpL + D_, INV64,
        x, nullptr, nullptr,
        conv_rows, conv_rows, nullptr, T_, D_, 3 * D_, D_, D_, 1, INV4096, nullptr, nullptr);

    const long DD = (long)D_ * D_;
    for (int i = 0; i < L_; ++i) {
        ln_k<<<T_, 256, 0, stream>>>(x, ln1g + i * D_, ln1b + i * D_, hH, hL);
        tr4_split_k<<<dim3(D_ / 32, D_ / 32, 4), 256, 0, stream>>>(
            Wq + i * DD, Wk + i * DD, Wv + i * DD, Wo + i * DD, w4H, w4L, D_, D_, DD);
        concat3_k<<<9, 256, 0, stream>>>(bq + i * D_, bk + i * D_, bv + i * D_, qkvb);
        // fused QKV: [T][2304] fp32
        mfma_gemm_k<<<dim3(3 * D_ / 128, T_ / 128, 1), 256, 0, stream>>>(
            hH, hL, w4H, w4L, qkvb, nullptr, nullptr, nullptr, 0.f,
            qkv, nullptr, nullptr,
            nullptr, nullptr, nullptr, T_, 3 * D_, D_, D_, 3 * D_, 0, INV64, nullptr, nullptr);
        flash_attn_k<<<B_ * H_ * (S_ / 64), 256, 0, stream>>>(qkv, obH, obL);
        mfma_gemm_k<<<dim3(D_ / 128, T_ / 128, 1), 256, 0, stream>>>(
            obH, obL, w4H + 3 * DD, w4L + 3 * DD, bo + i * D_, x, nullptr, nullptr, 0.f,
            x, nullptr, nullptr,
            nullptr, nullptr, nullptr, T_, D_, D_, D_, D_, 0, INV64, nullptr, nullptr);
        ln_k<<<T_, 256, 0, stream>>>(x, ln2g + i * D_, ln2b + i * D_, hH, hL);
        router_fused_k<<<T_ / 64, 256, 0, stream>>>(
            hH, hL, rw + (long)i * D_ * E_, rb + i * E_, cnt + i * E_, list, gate_slot);
        for (int e = 0; e < E_; ++e) {
            const float* w1 = ew1 + ((long)i * E_ + e) * D_ * F_;
            const float* w2 = ew2 + ((long)i * E_ + e) * F_ * D_;
            tr4_split_k<<<dim3(F_ / 32, D_ / 32, 1), 256, 0, stream>>>(
                w1, w1, w1, w1, e1H, e1L, D_, F_, 0);
            mfma_gemm_k<<<dim3(F_ / 128, T_ / 128, 1), 256, 0, stream>>>(
                hH, hL, e1H, e1L, eb1 + ((long)i * E_ + e) * F_, nullptr, nullptr, nullptr, 0.f,
                nullptr, h1H, h1L,
                list + e * T_, nullptr, cnt + i * E_ + e, T_, F_, D_, D_, F_, 1, INV64, nullptr, nullptr);
            tr4_split_k<<<dim3(D_ / 32, F_ / 32, 1), 256, 0, stream>>>(
                w2, w2, w2, w2, e2H, e2L, F_, D_, 0);
            // K-split z=4 (exact: output is atomic scatter; bias only from z==0)
            mfma_gemm_k<<<dim3(D_ / 128, T_ / 128, 4), 256, 0, stream>>>(
                h1H, h1L, e2H, e2L, eb2 + ((long)i * E_ + e) * D_, nullptr, nullptr, nullptr, 0.f,
                x, nullptr, nullptr,
                nullptr, nullptr, cnt + i * E_ + e, T_, D_, F_, F_, D_, 0, INV64,
                list + e * T_, gate_slot + e * T_);
        }
    }
    ln_k<<<T_, 256, 0, stream>>>(x, lnfg, lnfb, hH, hL);
    tr4_split_k<<<dim3(V_ / 32, D_ / 32, 1), 256, 0, stream>>>(
        outw, outw, outw, outw, owH, owL, D_, V_, 0);
    mfma_gemm_k<<<dim3(V_ / 128, T_ / 128, 1), 256, 0, stream>>>(
        hH, hL, owH, owL, outb, nullptr, nullptr, nullptr, 0.f,
        out, nullptr, nullptr,
        nullptr, nullptr, nullptr, T_, V_, D_, D_, V_, 0, INV64, nullptr, nullptr);
}